// Round 3
// baseline (226.836 us; speedup 1.0000x reference)
//
#include <hip/hip_runtime.h>
#include <hip/hip_bf16.h>
#include <math.h>

// SafetyLoss: quintic trajectories -> per-group SDF window -> trilinear sample
// -> exp cost -> per-trajectory sum.  OUTPUT IS FLOAT32 (round-5 finding).
//
// R8: single plain-launch kernel with a SOFTWARE grid barrier (atomic epoch
// counter, agent-scope sc1 atomics) replacing the 2-kernel split.
//   - R6 lesson: hipLaunchCooperativeKernel defeats graph timing (+35us).
//     This is the same grid.sync mechanism WITHOUT the coop launch API.
//   - co-residency: grid=256 blocks x 256 thr on 256 CUs -> 1 block/CU,
//     capacity ~8x; all blocks resident => spin barrier cannot starve.
//   - positions stay in REGISTERS across the barrier (posbuf eliminated);
//     build_coe runs once; one dispatch instead of two.
//   - bounded spin (fail loudly, never hang). AGENT-scope atomics are
//     required: volatile spin could hit stale per-XCD L2 forever (G16).
#define TRAJ 8
#define EV   30
#define NPT  (TRAJ*EV)  // 240 points per group
#define GCONST 256
#define MCONST 4
#define NXM  400
#define NYM  400
#define NZM  64
// VOX=0.2, D0=0.5, R=0.3, SGM_T=2.0, dt=2/30. coe in fp32 (contract off,
// ascending k = einsum match); downstream in f64 (passing numerics - frozen).

__device__ unsigned g_bar;  // zero at module load; monotonic epoch counter.
// Each launch adds exactly GCONST. Wraps after 2^32/256 launches (never hit).

__device__ __forceinline__ float ldf(const void* p, int idx, int isbf) {
    if (isbf) return __bfloat162float(((const __hip_bfloat16*)p)[idx]);
    return ((const float*)p)[idx];
}

__device__ __forceinline__ void resolve_ms(const void*& minb,
                                           const void*& shapes) {
    // min_bounds is all zeros; sdf_shapes starts with 400.0.
    if (*(const unsigned*)shapes == 0u) {
        const void* t = minb; minb = shapes; shapes = t;
    }
}

__device__ __forceinline__ int detect_bf16(const void* shapes) {
    return *(const unsigned*)shapes != 0x43C80000u;  // f32 400.0 word
}

// Cooperative: fp32 coefficients for this block's 8 trajectories.
// scoe layout: [(traj*3 + dim)*6 + j]
__device__ __forceinline__ void build_coe(const void* Df, const void* Dp,
                                          const void* L, int g, int isbf,
                                          float* sL, float* scoe, int t) {
#pragma clang fp contract(off)
    if (t < 36) sL[t] = ldf(L, t, isbf);
    __syncthreads();
    if (t < 144) {
        int traj = t / 18, rem = t % 18, i = rem / 6, j = rem % 6;
        int b = g * TRAJ + traj;
        float dv[6];
#pragma unroll
        for (int k = 0; k < 3; ++k) {
            dv[k]     = ldf(Df, b * 9 + i * 3 + k, isbf);
            dv[3 + k] = ldf(Dp, b * 9 + i * 3 + k, isbf);
        }
        float s = 0.f;
#pragma unroll
        for (int k = 0; k < 6; ++k) s = s + sL[j * 6 + k] * dv[k];  // ascending
        scoe[(traj * 3 + i) * 6 + j] = s;
    }
    __syncthreads();
}

// pos[i] = sum_k t^k * coe[k], f64 accumulation from fp32 coe.
__device__ __forceinline__ void eval_pos(const float* scoe, int traj, int e,
                                         double* p) {
    const double dt   = 2.0 / 30.0;
    const double step = (2.0 - dt) / 29.0;                    // np.linspace
    double tn = (e == EV - 1) ? 2.0 : dt + (double)e * step;  // exact endpoint
    double tk = 1.0;
    p[0] = p[1] = p[2] = 0.0;
#pragma unroll
    for (int k = 0; k < 6; ++k) {
        p[0] += tk * (double)scoe[(traj * 3 + 0) * 6 + k];
        p[1] += tk * (double)scoe[(traj * 3 + 1) * 6 + k];
        p[2] += tk * (double)scoe[(traj * 3 + 2) * 6 + k];
        tk *= tn;
    }
}

// Software grid barrier: thread 0 arrives+spins; block waits at syncthreads.
// AGENT scope (sc1) is mandatory: per-XCD L2s are not coherent; relaxed or
// volatile polling could spin on a stale line forever.
__device__ __forceinline__ void grid_barrier(int t) {
    __syncthreads();
    if (t == 0) {
        __threadfence();  // release: write back dirty L2 (groupA) to L3
        unsigned ticket = __hip_atomic_fetch_add(
            &g_bar, 1u, __ATOMIC_ACQ_REL, __HIP_MEMORY_SCOPE_AGENT);
        unsigned target = ticket - (ticket & (GCONST - 1)) + GCONST;
        unsigned spins = 0;
        while (__hip_atomic_load(&g_bar, __ATOMIC_ACQUIRE,
                                 __HIP_MEMORY_SCOPE_AGENT) < target) {
            if (++spins > (4u << 20)) break;  // failsafe: wrong > hung
            __builtin_amdgcn_s_sleep(1);
        }
        __threadfence();  // acquire: invalidate L1/L2 before data reads
    }
    __syncthreads();
}

// K: fused pipeline with software grid barrier.
__global__ __launch_bounds__(256) void k_fused(
    const void* Df, const void* Dp, const void* L, const void* minb_in,
    const void* shapes_in, const int* map_id, const void* sdf, int* groupA,
    float* out) {
    __shared__ float  sL[36];
    __shared__ float  scoe[144];
    __shared__ double sredd[3][2][4];  // [dim][min|max][wave] partials
    __shared__ int    sWin[GCONST][6];
    __shared__ int    sredi[3][4];     // [dim][wave] int-max partials
    __shared__ double scost[NPT];
    const void* minb = minb_in; const void* shapes = shapes_in;
    resolve_ms(minb, shapes);
    int g = blockIdx.x, t = threadIdx.x;
    int lane = t & 63, wid = t >> 6;
    int isbf = detect_bf16(shapes);

    // ---- Phase 1: coefficients + positions (REGISTERS) + group bounds ----
    build_coe(Df, Dp, L, g, isbf, sL, scoe, t);

    double p[3] = {0.0, 0.0, 0.0};
    if (t < NPT) eval_pos(scoe, t / EV, t % EV, p);
    double mn[3], mx[3];
#pragma unroll
    for (int i = 0; i < 3; ++i) {
        mn[i] = (t < NPT) ? p[i] : 1e300;
        mx[i] = (t < NPT) ? p[i] : -1e300;
    }
#pragma unroll
    for (int off = 32; off; off >>= 1)
#pragma unroll
        for (int i = 0; i < 3; ++i) {
            mn[i] = fmin(mn[i], __shfl_xor(mn[i], off));
            mx[i] = fmax(mx[i], __shfl_xor(mx[i], off));
        }
    if (lane == 0)
#pragma unroll
        for (int i = 0; i < 3; ++i) {
            sredd[i][0][wid] = mn[i];
            sredd[i][1][wid] = mx[i];
        }
    __syncthreads();
    if (t == 0) {
        int mid = min(max(map_id[g], 0), MCONST - 1);
#pragma unroll
        for (int i = 0; i < 3; ++i) {
            double a = fmin(fmin(sredd[i][0][0], sredd[i][0][1]),
                            fmin(sredd[i][0][2], sredd[i][0][3]));
            double b = fmax(fmax(sredd[i][1][0], sredd[i][1][1]),
                            fmax(sredd[i][1][2], sredd[i][1][3]));
            double mb = (double)ldf(minb, mid * 3 + i, isbf);
            groupA[g * 8 + i]     = (int)trunc((a - mb) / 0.2);
            groupA[g * 8 + 4 + i] = (int)trunc((b - mb) / 0.2);
        }
    }

    grid_barrier(t);  // all groupA visible device-wide

    // ---- Phase 2 prologue: global span/shift (thread t handles group t,
    // integer-exact, identical result in every block) ----
    int mn0[3], mx0[3], v[3];
#pragma unroll
    for (int i = 0; i < 3; ++i) {
        mn0[i] = groupA[t * 8 + i];
        mx0[i] = groupA[t * 8 + 4 + i];
        v[i]   = mx0[i] - mn0[i];
    }
#pragma unroll
    for (int off = 32; off; off >>= 1)
#pragma unroll
        for (int i = 0; i < 3; ++i) v[i] = max(v[i], __shfl_xor(v[i], off));
    if (lane == 0)
#pragma unroll
        for (int i = 0; i < 3; ++i) sredi[i][wid] = v[i];
    __syncthreads();
    int span[3];
#pragma unroll
    for (int i = 0; i < 3; ++i)
        span[i] = max(max(sredi[i][0], sredi[i][1]),
                      max(sredi[i][2], sredi[i][3]));
    __syncthreads();  // sredi reused below

    {
        int mid_t = min(max(map_id[t], 0), MCONST - 1);
#pragma unroll
        for (int i = 0; i < 3; ++i) {
            int c   = (mn0[i] + mx0[i]) >> 1;  // floor div
            int h   = span[i] >> 1;            // max_spans // 2 (nonneg)
            int mn1 = c - h - 5, mx1 = c + h + 5;
            int nmn = mn1 > 0 ? mn1 : 0;
            int mx2 = mx1 + (nmn - mn1);
            int shp = (int)ldf(shapes, mid_t * 3 + i, isbf);
            int nmx = mx2 < shp ? mx2 : shp;
            int mn3 = nmn - (mx2 - nmx);
            sWin[t][i]     = mn3;
            sWin[t][3 + i] = nmx;  // mx3
            v[i]           = mn3 < 0 ? -mn3 : 0;
        }
    }
#pragma unroll
    for (int off = 32; off; off >>= 1)
#pragma unroll
        for (int i = 0; i < 3; ++i) v[i] = max(v[i], __shfl_xor(v[i], off));
    if (lane == 0)
#pragma unroll
        for (int i = 0; i < 3; ++i) sredi[i][wid] = v[i];
    __syncthreads();  // also guards sWin writes before sWin[g] reads
    int mnf[3], lsh[3];
#pragma unroll
    for (int i = 0; i < 3; ++i) {
        int shift = max(max(sredi[i][0], sredi[i][1]),
                        max(sredi[i][2], sredi[i][3]));
        int m  = sWin[g][i] + shift;  // mn_final = mn3 + shift
        mnf[i] = m;
        lsh[i] = sWin[g][3 + i] - m;  // lshape = mx3 - mn_final
    }

    // ---- Phase 2: sampling with REGISTER positions (bit-exact reuse) ----
    int mid = min(max(map_id[g], 0), MCONST - 1);
    if (t < NPT) {
        double f[3];
        int    l0[3];
        bool   valid = true;
#pragma unroll
        for (int i = 0; i < 3; ++i) {
            double mb = (double)ldf(minb, mid * 3 + i, isbf);
            double gr = (p[i] - ((double)mnf[i] * 0.2 + mb)) / 0.2;
            double gp = 2.0 * gr / (double)(lsh[i] - 1) - 1.0;
            valid = valid && (gp < 0.99) && (gp > -0.99);
            double fl = floor(gr);
            l0[i] = (int)fl;
            f[i]  = gr - fl;
        }
        // Batch the 8 corner gathers: compute all indices/masks, then issue
        // all loads unconditionally (clamped => always in-map => safe), then
        // masked accumulate. 8 loads in flight instead of 8 serialized.
        const int mbase = mid * (NZM * NYM * NXM);
        int  idx8[8];
        bool inb8[8];
        double w8[8];
#pragma unroll
        for (int c = 0; c < 8; ++c) {
            int dx = c & 1, dy = (c >> 1) & 1, dz = (c >> 2) & 1;
            int ilx = l0[0] + dx, ily = l0[1] + dy, ilz = l0[2] + dz;
            inb8[c] = (ilx >= 0 && ilx < lsh[0]) && (ily >= 0 && ily < lsh[1])
                   && (ilz >= 0 && ilz < lsh[2]);
            int gx = min(max(ilx + mnf[0], 0), NXM - 1);
            int gy = min(max(ily + mnf[1], 0), NYM - 1);
            int gz = min(max(ilz + mnf[2], 0), NZM - 1);
            idx8[c] = mbase + (gz * NYM + gy) * NXM + gx;
            w8[c] = (dx ? f[0] : 1.0 - f[0]) * (dy ? f[1] : 1.0 - f[1])
                  * (dz ? f[2] : 1.0 - f[2]);
        }
        float v8[8];
#pragma unroll
        for (int c = 0; c < 8; ++c) v8[c] = ldf(sdf, idx8[c], isbf);
        double acc = 0.0;
#pragma unroll
        for (int c = 0; c < 8; ++c)
            if (inb8[c]) acc += w8[c] * (double)v8[c];

        double cost = valid ? exp(-(acc - 0.5) / 0.3) : 0.0;
        scost[t] = cost * (2.0 / 30.0);  // cost * dt
    }
    __syncthreads();
    if (t < TRAJ) {
        double s = 0.0;
#pragma unroll
        for (int e = 0; e < EV; ++e) s += scost[t * EV + e];
        out[g * TRAJ + t] = (float)s;  // FLOAT32 output
    }
}

extern "C" void kernel_launch(void* const* d_in, const int* in_sizes, int n_in,
                              void* d_out, int out_size, void* d_ws,
                              size_t ws_size, hipStream_t stream) {
    // Inputs identified by SIZE RANKING (stable, descending) — order/unit
    // invariant: rank0 sdf_maps; rank1,2 Df,Dp; rank3 map_id; rank4 L;
    // rank5,6 min_bounds/sdf_shapes (resolved on device by content).
    int order[16];
    int n = n_in < 16 ? n_in : 16;
    for (int i = 0; i < n; ++i) order[i] = i;
    for (int i = 1; i < n; ++i) {
        int oi = order[i], j = i - 1;
        while (j >= 0 && in_sizes[order[j]] < in_sizes[oi]) {
            order[j + 1] = order[j]; --j;
        }
        order[j + 1] = oi;
    }
    const void* sdf    = d_in[order[0]];
    const void* Df     = d_in[order[1]];
    const void* Dp     = d_in[order[2]];
    const int*  map_id = (const int*)d_in[order[3]];
    const void* L      = d_in[order[4]];
    const void* minb   = d_in[order[5]];
    const void* shapes = d_in[order[6 < n ? 6 : 5]];

    // ws: groupA[G*8] ints only (8 KB); written (phase 1) before read
    // (phase 2) within the single dispatch, ordered by the grid barrier.
    int*   groupA = (int*)d_ws;
    float* outp   = (float*)d_out;

    k_fused<<<GCONST, 256, 0, stream>>>(Df, Dp, L, minb, shapes, map_id, sdf,
                                        groupA, outp);
    (void)out_size; (void)ws_size;
}

// Round 4
// 215.352 us; speedup vs baseline: 1.0533x; 1.0533x over previous
//
#include <hip/hip_runtime.h>
#include <hip/hip_bf16.h>
#include <math.h>

// SafetyLoss: quintic trajectories -> per-group SDF window -> trilinear sample
// -> exp cost -> per-trajectory sum.  OUTPUT IS FLOAT32 (round-5 finding).
//
// R9: REVERT to R7 (best measured, 216.1us). Grid-sync experiments closed:
//   - R6 hipLaunchCooperativeKernel: +35us (defeats graph timing)
//   - R8 software spin barrier:      +10us (256 spinners on one L3 line +
//     dispatch ramp paid in-kernel; the HW end-of-kernel barrier is cheaper)
// Structure: 2-kernel pipeline, wave __shfl_xor reductions, K1 stores f64
// positions to workspace, K3 reloads them (bit-exact; drops build_coe/
// eval_pos + 2 barriers from K3). ws_size-guarded fallback to recompute.
// Iteration floor: ~196us harness poison fills at 83% HBM peak (invariant).
#define TRAJ 8
#define EV   30
#define NPT  (TRAJ*EV)  // 240 points per group
#define GCONST 256
#define MCONST 4
#define NXM  400
#define NYM  400
#define NZM  64
// VOX=0.2, D0=0.5, R=0.3, SGM_T=2.0, dt=2/30. coe in fp32 (contract off,
// ascending k = einsum match); downstream in f64 (passing numerics - frozen).

__device__ __forceinline__ float ldf(const void* p, int idx, int isbf) {
    if (isbf) return __bfloat162float(((const __hip_bfloat16*)p)[idx]);
    return ((const float*)p)[idx];
}

__device__ __forceinline__ void resolve_ms(const void*& minb,
                                           const void*& shapes) {
    // min_bounds is all zeros; sdf_shapes starts with 400.0.
    if (*(const unsigned*)shapes == 0u) {
        const void* t = minb; minb = shapes; shapes = t;
    }
}

__device__ __forceinline__ int detect_bf16(const void* shapes) {
    return *(const unsigned*)shapes != 0x43C80000u;  // f32 400.0 word
}

// Cooperative: fp32 coefficients for this block's 8 trajectories.
// scoe layout: [(traj*3 + dim)*6 + j]
__device__ __forceinline__ void build_coe(const void* Df, const void* Dp,
                                          const void* L, int g, int isbf,
                                          float* sL, float* scoe, int t) {
#pragma clang fp contract(off)
    if (t < 36) sL[t] = ldf(L, t, isbf);
    __syncthreads();
    if (t < 144) {
        int traj = t / 18, rem = t % 18, i = rem / 6, j = rem % 6;
        int b = g * TRAJ + traj;
        float dv[6];
#pragma unroll
        for (int k = 0; k < 3; ++k) {
            dv[k]     = ldf(Df, b * 9 + i * 3 + k, isbf);
            dv[3 + k] = ldf(Dp, b * 9 + i * 3 + k, isbf);
        }
        float s = 0.f;
#pragma unroll
        for (int k = 0; k < 6; ++k) s = s + sL[j * 6 + k] * dv[k];  // ascending
        scoe[(traj * 3 + i) * 6 + j] = s;
    }
    __syncthreads();
}

// pos[i] = sum_k t^k * coe[k], f64 accumulation from fp32 coe.
__device__ __forceinline__ void eval_pos(const float* scoe, int traj, int e,
                                         double* p) {
    const double dt   = 2.0 / 30.0;
    const double step = (2.0 - dt) / 29.0;                    // np.linspace
    double tn = (e == EV - 1) ? 2.0 : dt + (double)e * step;  // exact endpoint
    double tk = 1.0;
    p[0] = p[1] = p[2] = 0.0;
#pragma unroll
    for (int k = 0; k < 6; ++k) {
        p[0] += tk * (double)scoe[(traj * 3 + 0) * 6 + k];
        p[1] += tk * (double)scoe[(traj * 3 + 1) * 6 + k];
        p[2] += tk * (double)scoe[(traj * 3 + 2) * 6 + k];
        tk *= tn;
    }
}

// Shared sampling epilogue: 8-gather trilinear -> exp cost -> per-traj sums.
__device__ __forceinline__ void sample_and_reduce(
    const void* minb, const void* shapes, const void* sdf, int isbf, int mid,
    int g, int t, const int* mnf, const int* lsh, const double* p,
    double* scost, float* out) {
    if (t < NPT) {
        double f[3];
        int    l0[3];
        bool   valid = true;
#pragma unroll
        for (int i = 0; i < 3; ++i) {
            double mb = (double)ldf(minb, mid * 3 + i, isbf);
            double gr = (p[i] - ((double)mnf[i] * 0.2 + mb)) / 0.2;
            double gp = 2.0 * gr / (double)(lsh[i] - 1) - 1.0;
            valid = valid && (gp < 0.99) && (gp > -0.99);
            double fl = floor(gr);
            l0[i] = (int)fl;
            f[i]  = gr - fl;
        }
        // Batch the 8 corner gathers: compute all indices/masks, then issue
        // all loads unconditionally (clamped => always in-map => safe), then
        // masked accumulate. 8 loads in flight instead of 8 serialized.
        const int mbase = mid * (NZM * NYM * NXM);
        int  idx8[8];
        bool inb8[8];
        double w8[8];
#pragma unroll
        for (int c = 0; c < 8; ++c) {
            int dx = c & 1, dy = (c >> 1) & 1, dz = (c >> 2) & 1;
            int ilx = l0[0] + dx, ily = l0[1] + dy, ilz = l0[2] + dz;
            inb8[c] = (ilx >= 0 && ilx < lsh[0]) && (ily >= 0 && ily < lsh[1])
                   && (ilz >= 0 && ilz < lsh[2]);
            int gx = min(max(ilx + mnf[0], 0), NXM - 1);
            int gy = min(max(ily + mnf[1], 0), NYM - 1);
            int gz = min(max(ilz + mnf[2], 0), NZM - 1);
            idx8[c] = mbase + (gz * NYM + gy) * NXM + gx;
            w8[c] = (dx ? f[0] : 1.0 - f[0]) * (dy ? f[1] : 1.0 - f[1])
                  * (dz ? f[2] : 1.0 - f[2]);
        }
        float v8[8];
#pragma unroll
        for (int c = 0; c < 8; ++c) v8[c] = ldf(sdf, idx8[c], isbf);
        double acc = 0.0;
#pragma unroll
        for (int c = 0; c < 8; ++c)
            if (inb8[c]) acc += w8[c] * (double)v8[c];

        double cost = valid ? exp(-(acc - 0.5) / 0.3) : 0.0;
        scost[t] = cost * (2.0 / 30.0);  // cost * dt
    }
    __syncthreads();
    if (t < TRAJ) {
        double s = 0.0;
#pragma unroll
        for (int e = 0; e < EV; ++e) s += scost[t * EV + e];
        out[g * TRAJ + t] = (float)s;  // FLOAT32 output
    }
}

// K1: per-group positions -> wave-reduce min/max -> mn0/mx0 into groupA.
// Also stores the f64 positions to posbuf (reused bit-exact by K3).
__global__ __launch_bounds__(256) void k_minmax(
    const void* Df, const void* Dp, const void* L, const void* minb_in,
    const void* shapes_in, const int* map_id, int* groupA, double* posbuf) {
    __shared__ float  sL[36];
    __shared__ float  scoe[144];
    __shared__ double sredd[3][2][4];  // [dim][min|max][wave] partials
    const void* minb = minb_in; const void* shapes = shapes_in;
    resolve_ms(minb, shapes);
    int g = blockIdx.x, t = threadIdx.x;
    int lane = t & 63, wid = t >> 6;
    int isbf = detect_bf16(shapes);
    build_coe(Df, Dp, L, g, isbf, sL, scoe, t);

    double p[3] = {0.0, 0.0, 0.0};
    if (t < NPT) {
        eval_pos(scoe, t / EV, t % EV, p);
        if (posbuf) {
            double* dst = posbuf + (size_t)g * NPT * 3 + (size_t)t * 3;
            dst[0] = p[0]; dst[1] = p[1]; dst[2] = p[2];
        }
    }
    double mn[3], mx[3];
#pragma unroll
    for (int i = 0; i < 3; ++i) {
        mn[i] = (t < NPT) ? p[i] : 1e300;
        mx[i] = (t < NPT) ? p[i] : -1e300;
    }
#pragma unroll
    for (int off = 32; off; off >>= 1)
#pragma unroll
        for (int i = 0; i < 3; ++i) {
            mn[i] = fmin(mn[i], __shfl_xor(mn[i], off));
            mx[i] = fmax(mx[i], __shfl_xor(mx[i], off));
        }
    if (lane == 0)
#pragma unroll
        for (int i = 0; i < 3; ++i) {
            sredd[i][0][wid] = mn[i];
            sredd[i][1][wid] = mx[i];
        }
    __syncthreads();
    if (t == 0) {
        int mid = min(max(map_id[g], 0), MCONST - 1);
#pragma unroll
        for (int i = 0; i < 3; ++i) {
            double a = fmin(fmin(sredd[i][0][0], sredd[i][0][1]),
                            fmin(sredd[i][0][2], sredd[i][0][3]));
            double b = fmax(fmax(sredd[i][1][0], sredd[i][1][1]),
                            fmax(sredd[i][1][2], sredd[i][1][3]));
            double mb = (double)ldf(minb, mid * 3 + i, isbf);
            groupA[g * 8 + i]     = (int)trunc((a - mb) / 0.2);
            groupA[g * 8 + 4 + i] = (int)trunc((b - mb) / 0.2);
        }
    }
}

// K3: window prologue (global span/shift, redundant per block, integer-exact)
// + sampling.  USEPOS: reload f64 positions from posbuf instead of recompute.
template <bool USEPOS>
__global__ __launch_bounds__(256) void k_sample(
    const void* Df, const void* Dp, const void* L, const void* minb_in,
    const void* shapes_in, const int* map_id, const void* sdf,
    const int* groupA, const double* posbuf, float* out) {
    __shared__ float  sL[36];
    __shared__ float  scoe[144];
    __shared__ double scost[NPT];
    __shared__ int    sWin[GCONST][6];
    __shared__ int    sredi[3][4];  // [dim][wave] int-max partials
    const void* minb = minb_in; const void* shapes = shapes_in;
    resolve_ms(minb, shapes);
    int g = blockIdx.x, t = threadIdx.x;
    int lane = t & 63, wid = t >> 6;
    int isbf = detect_bf16(shapes);

    // ---- Window prologue: thread t handles group t (integer-exact; every
    // block computes identical global span/shift from K1's groupA). ----
    int mn0[3], mx0[3], v[3];
#pragma unroll
    for (int i = 0; i < 3; ++i) {
        mn0[i] = groupA[t * 8 + i];
        mx0[i] = groupA[t * 8 + 4 + i];
        v[i]   = mx0[i] - mn0[i];
    }
#pragma unroll
    for (int off = 32; off; off >>= 1)
#pragma unroll
        for (int i = 0; i < 3; ++i) v[i] = max(v[i], __shfl_xor(v[i], off));
    if (lane == 0)
#pragma unroll
        for (int i = 0; i < 3; ++i) sredi[i][wid] = v[i];
    __syncthreads();
    int span[3];
#pragma unroll
    for (int i = 0; i < 3; ++i)
        span[i] = max(max(sredi[i][0], sredi[i][1]),
                      max(sredi[i][2], sredi[i][3]));
    __syncthreads();  // sredi reused below

    {
        int mid_t = min(max(map_id[t], 0), MCONST - 1);
#pragma unroll
        for (int i = 0; i < 3; ++i) {
            int c   = (mn0[i] + mx0[i]) >> 1;  // floor div
            int h   = span[i] >> 1;            // max_spans // 2 (nonneg)
            int mn1 = c - h - 5, mx1 = c + h + 5;
            int nmn = mn1 > 0 ? mn1 : 0;
            int mx2 = mx1 + (nmn - mn1);
            int shp = (int)ldf(shapes, mid_t * 3 + i, isbf);
            int nmx = mx2 < shp ? mx2 : shp;
            int mn3 = nmn - (mx2 - nmx);
            sWin[t][i]     = mn3;
            sWin[t][3 + i] = nmx;  // mx3
            v[i]           = mn3 < 0 ? -mn3 : 0;
        }
    }
#pragma unroll
    for (int off = 32; off; off >>= 1)
#pragma unroll
        for (int i = 0; i < 3; ++i) v[i] = max(v[i], __shfl_xor(v[i], off));
    if (lane == 0)
#pragma unroll
        for (int i = 0; i < 3; ++i) sredi[i][wid] = v[i];
    __syncthreads();  // also guards sWin writes before sWin[g] reads
    int mnf[3], lsh[3];
#pragma unroll
    for (int i = 0; i < 3; ++i) {
        int shift = max(max(sredi[i][0], sredi[i][1]),
                        max(sredi[i][2], sredi[i][3]));
        int m  = sWin[g][i] + shift;  // mn_final = mn3 + shift
        mnf[i] = m;
        lsh[i] = sWin[g][3 + i] - m;  // lshape = mx3 - mn_final
    }

    // ---- Positions: reload (bit-exact) or recompute ----
    double p[3] = {0.0, 0.0, 0.0};
    if (USEPOS) {
        if (t < NPT) {
            const double* src = posbuf + (size_t)g * NPT * 3 + (size_t)t * 3;
            p[0] = src[0]; p[1] = src[1]; p[2] = src[2];
        }
    } else {
        build_coe(Df, Dp, L, g, isbf, sL, scoe, t);
        if (t < NPT) eval_pos(scoe, t / EV, t % EV, p);
    }

    int mid = min(max(map_id[g], 0), MCONST - 1);
    sample_and_reduce(minb, shapes, sdf, isbf, mid, g, t, mnf, lsh, p, scost,
                      out);
}

extern "C" void kernel_launch(void* const* d_in, const int* in_sizes, int n_in,
                              void* d_out, int out_size, void* d_ws,
                              size_t ws_size, hipStream_t stream) {
    // Inputs identified by SIZE RANKING (stable, descending) — order/unit
    // invariant: rank0 sdf_maps; rank1,2 Df,Dp; rank3 map_id; rank4 L;
    // rank5,6 min_bounds/sdf_shapes (resolved on device by content).
    int order[16];
    int n = n_in < 16 ? n_in : 16;
    for (int i = 0; i < n; ++i) order[i] = i;
    for (int i = 1; i < n; ++i) {
        int oi = order[i], j = i - 1;
        while (j >= 0 && in_sizes[order[j]] < in_sizes[oi]) {
            order[j + 1] = order[j]; --j;
        }
        order[j + 1] = oi;
    }
    const void* sdf    = d_in[order[0]];
    const void* Df     = d_in[order[1]];
    const void* Dp     = d_in[order[2]];
    const int*  map_id = (const int*)d_in[order[3]];
    const void* L      = d_in[order[4]];
    const void* minb   = d_in[order[5]];
    const void* shapes = d_in[order[6 < n ? 6 : 5]];

    // ws layout: [0,8KB) groupA ints; [8KB, 8KB+1.44MB) f64 positions.
    // Both written (K1) before read (K3) within this call; harness poison
    // between iterations is irrelevant to intra-call ordering.
    const size_t posOff   = (size_t)GCONST * 8 * sizeof(int);        // 8 KB
    const size_t posBytes = (size_t)GCONST * NPT * 3 * sizeof(double);
    int*    groupA = (int*)d_ws;
    bool    usepos = (ws_size >= posOff + posBytes);
    double* posbuf = usepos ? (double*)((char*)d_ws + posOff) : nullptr;
    float*  outp   = (float*)d_out;

    k_minmax<<<GCONST, 256, 0, stream>>>(Df, Dp, L, minb, shapes, map_id,
                                         groupA, posbuf);
    if (usepos)
        k_sample<true><<<GCONST, 256, 0, stream>>>(Df, Dp, L, minb, shapes,
                                                   map_id, sdf, groupA, posbuf,
                                                   outp);
    else
        k_sample<false><<<GCONST, 256, 0, stream>>>(Df, Dp, L, minb, shapes,
                                                    map_id, sdf, groupA,
                                                    nullptr, outp);
    (void)out_size;
}